// Round 1
// baseline (286.400 us; speedup 1.0000x reference)
//
#include <hip/hip_runtime.h>

typedef __attribute__((ext_vector_type(8))) short short8_t;
typedef __attribute__((ext_vector_type(4))) float f32x4_t;

#define NOUT 8192
#define NIN 32768
#define MTOT 262144.0f   // B * NOUT

static __device__ __forceinline__ float bf2f(ushort u) {
    union { float f; unsigned int i; } x; x.i = ((unsigned int)u) << 16; return x.f;
}
static __device__ __forceinline__ ushort f2bf(float f) {
    union { float f; unsigned int i; } x; x.f = f;
    unsigned int r = x.i + 0x7fffu + ((x.i >> 16) & 1u);
    return (ushort)(r >> 16);
}

// ---- x [32][32][32768] f32  ->  xt [32768][1024] bf16 (row = b*32+i) ----
__global__ __launch_bounds__(256) void transpose_x_kernel(
    const float* __restrict__ x, ushort* __restrict__ xt)
{
    __shared__ ushort T[64][66];
    const int tid = threadIdx.x;
    const int n0 = blockIdx.x * 64, c0 = blockIdx.y * 64;
    const int lane64 = tid & 63, rb = (tid >> 6) * 16;
    #pragma unroll
    for (int r = 0; r < 16; ++r) {
        int c_l = rb + r;
        T[c_l][lane64] = f2bf(x[(size_t)(c0 + c_l) * NIN + n0 + lane64]);
    }
    __syncthreads();
    #pragma unroll
    for (int r = 0; r < 16; ++r) {
        int n_l = rb + r;
        xt[(size_t)(n0 + n_l) * 1024 + c0 + lane64] = T[lane64][n_l];
    }
}

// ---- weight prep: W1->[9][64][32], W2->[18][64][32], We->[64][32], all bf16 ----
__global__ __launch_bounds__(256) void prep_w_kernel(
    const float* __restrict__ W1, const float* __restrict__ W2,
    const float* __restrict__ We,
    ushort* __restrict__ w1p, ushort* __restrict__ w2p, ushort* __restrict__ wep)
{
    int t = blockIdx.x * 256 + threadIdx.x;
    const int N1 = 9 * 64 * 32, N2 = 18 * 64 * 32, N3 = 64 * 32;
    if (t < N1) {
        int k = t >> 11, rem = t & 2047, o = rem >> 5, i = rem & 31;
        w1p[t] = f2bf(W1[o * 288 + i * 9 + k]);
    } else if (t < N1 + N2) {
        int t2 = t - N1;
        int s = t2 >> 11, rem = t2 & 2047, o = rem >> 5, i = rem & 31;
        int ci = (s & 1) * 32 + i, k = s >> 1;
        w2p[t2] = f2bf(W2[o * 576 + ci * 9 + k]);
    } else if (t < N1 + N2 + N3) {
        int t3 = t - N1 - N2;
        wep[t3] = f2bf(We[t3]);
    }
}

// ---- conv1: out1[n][(b,o)] = sum_{i,k} xt[idx1[n,k]][(b,i)] * W1[o,i,k] ----
__global__ __launch_bounds__(256) void conv1_kernel(
    const ushort* __restrict__ xt, const int* __restrict__ idx1,
    const ushort* __restrict__ w1p, ushort* __restrict__ out1)
{
    __shared__ ushort As[256 * 40];
    __shared__ ushort Ws[64 * 40];
    const int tid = threadIdx.x;
    const int lane = tid & 63, wv = tid >> 6;
    const int nbase = blockIdx.x * 8;
    const int n_l = tid >> 5, b = tid & 31;
    f32x4_t acc[4][4];
    #pragma unroll
    for (int m = 0; m < 4; ++m)
        #pragma unroll
        for (int nt = 0; nt < 4; ++nt) acc[m][nt] = (f32x4_t){0.f, 0.f, 0.f, 0.f};

    for (int k = 0; k < 9; ++k) {
        int rrow = idx1[(nbase + n_l) * 9 + k];
        const int4* src = (const int4*)(xt + (size_t)rrow * 1024 + b * 32);
        int4* dst = (int4*)(As + (n_l * 32 + b) * 40);
        #pragma unroll
        for (int j = 0; j < 4; ++j) dst[j] = src[j];
        {
            int o = tid >> 2, seg = tid & 3;
            *(int4*)(Ws + o * 40 + seg * 8) =
                *(const int4*)(w1p + k * 2048 + o * 32 + seg * 8);
        }
        __syncthreads();
        short8_t af[4], bfr[4];
        #pragma unroll
        for (int m = 0; m < 4; ++m)
            af[m] = *(const short8_t*)(As + (wv * 64 + m * 16 + (lane & 15)) * 40 + (lane >> 4) * 8);
        #pragma unroll
        for (int nt = 0; nt < 4; ++nt)
            bfr[nt] = *(const short8_t*)(Ws + (nt * 16 + (lane & 15)) * 40 + (lane >> 4) * 8);
        #pragma unroll
        for (int m = 0; m < 4; ++m)
            #pragma unroll
            for (int nt = 0; nt < 4; ++nt)
                acc[m][nt] = __builtin_amdgcn_mfma_f32_16x16x32_bf16(af[m], bfr[nt], acc[m][nt], 0, 0, 0);
        __syncthreads();
    }
    #pragma unroll
    for (int m = 0; m < 4; ++m)
        #pragma unroll
        for (int nt = 0; nt < 4; ++nt)
            #pragma unroll
            for (int j = 0; j < 4; ++j) {
                int row = wv * 64 + m * 16 + (lane >> 4) * 4 + j;
                int nl = row >> 5, bb = row & 31, col = nt * 16 + (lane & 15);
                out1[(size_t)(nbase + nl) * 2048 + bb * 64 + col] = f2bf(acc[m][nt][j]);
            }
}

// ---- conv2: out2[n][(b,o)] = sum_{i<64,k} out1n[idx2[n,k]][(b,i)] * W2[o,i,k] ----
__global__ __launch_bounds__(256) void conv2_kernel(
    const ushort* __restrict__ out1n, const int* __restrict__ idx2,
    const ushort* __restrict__ w2p, ushort* __restrict__ out2)
{
    __shared__ ushort As[256 * 40];
    __shared__ ushort Ws[64 * 40];
    const int tid = threadIdx.x;
    const int lane = tid & 63, wv = tid >> 6;
    const int nbase = blockIdx.x * 8;
    const int n_l = tid >> 5, b = tid & 31;
    f32x4_t acc[4][4];
    #pragma unroll
    for (int m = 0; m < 4; ++m)
        #pragma unroll
        for (int nt = 0; nt < 4; ++nt) acc[m][nt] = (f32x4_t){0.f, 0.f, 0.f, 0.f};

    for (int s = 0; s < 18; ++s) {
        int k = s >> 1, h = s & 1;
        int rrow = idx2[(nbase + n_l) * 9 + k];
        const int4* src = (const int4*)(out1n + (size_t)rrow * 2048 + b * 64 + h * 32);
        int4* dst = (int4*)(As + (n_l * 32 + b) * 40);
        #pragma unroll
        for (int j = 0; j < 4; ++j) dst[j] = src[j];
        {
            int o = tid >> 2, seg = tid & 3;
            *(int4*)(Ws + o * 40 + seg * 8) =
                *(const int4*)(w2p + s * 2048 + o * 32 + seg * 8);
        }
        __syncthreads();
        short8_t af[4], bfr[4];
        #pragma unroll
        for (int m = 0; m < 4; ++m)
            af[m] = *(const short8_t*)(As + (wv * 64 + m * 16 + (lane & 15)) * 40 + (lane >> 4) * 8);
        #pragma unroll
        for (int nt = 0; nt < 4; ++nt)
            bfr[nt] = *(const short8_t*)(Ws + (nt * 16 + (lane & 15)) * 40 + (lane >> 4) * 8);
        #pragma unroll
        for (int m = 0; m < 4; ++m)
            #pragma unroll
            for (int nt = 0; nt < 4; ++nt)
                acc[m][nt] = __builtin_amdgcn_mfma_f32_16x16x32_bf16(af[m], bfr[nt], acc[m][nt], 0, 0, 0);
        __syncthreads();
    }
    #pragma unroll
    for (int m = 0; m < 4; ++m)
        #pragma unroll
        for (int nt = 0; nt < 4; ++nt)
            #pragma unroll
            for (int j = 0; j < 4; ++j) {
                int row = wv * 64 + m * 16 + (lane >> 4) * 4 + j;
                int nl = row >> 5, bb = row & 31, col = nt * 16 + (lane & 15);
                out2[(size_t)(nbase + nl) * 2048 + bb * 64 + col] = f2bf(acc[m][nt][j]);
            }
}

// ---- identity: identt[n][(b,o)] = sum_i (mean_kp xt[pool_idx[n,kp]][(b,i)]) * We[o,i] ----
__global__ __launch_bounds__(256) void ident_kernel(
    const ushort* __restrict__ xt, const int* __restrict__ pool_idx,
    const ushort* __restrict__ wep, ushort* __restrict__ identt)
{
    __shared__ ushort As[256 * 40];
    __shared__ ushort Ws[64 * 40];
    const int tid = threadIdx.x;
    const int lane = tid & 63, wv = tid >> 6;
    const int nbase = blockIdx.x * 8;
    const int n_l = tid >> 5, b = tid & 31;

    float pa[32];
    #pragma unroll
    for (int i = 0; i < 32; ++i) pa[i] = 0.f;
    for (int kp = 0; kp < 4; ++kp) {
        int rrow = pool_idx[(nbase + n_l) * 4 + kp];
        const int4* src = (const int4*)(xt + (size_t)rrow * 1024 + b * 32);
        #pragma unroll
        for (int j = 0; j < 4; ++j) {
            int4 v = src[j];
            const ushort* pv = (const ushort*)&v;
            #pragma unroll
            for (int e = 0; e < 8; ++e) pa[j * 8 + e] += bf2f(pv[e]);
        }
    }
    {
        int4* dst = (int4*)(As + (n_l * 32 + b) * 40);
        #pragma unroll
        for (int j = 0; j < 4; ++j) {
            int4 v; ushort* pv = (ushort*)&v;
            #pragma unroll
            for (int e = 0; e < 8; ++e) pv[e] = f2bf(pa[j * 8 + e] * 0.25f);
            dst[j] = v;
        }
    }
    {
        int o = tid >> 2, seg = tid & 3;
        *(int4*)(Ws + o * 40 + seg * 8) = *(const int4*)(wep + o * 32 + seg * 8);
    }
    __syncthreads();

    f32x4_t acc[4][4];
    #pragma unroll
    for (int m = 0; m < 4; ++m)
        #pragma unroll
        for (int nt = 0; nt < 4; ++nt) acc[m][nt] = (f32x4_t){0.f, 0.f, 0.f, 0.f};
    short8_t af[4], bfr[4];
    #pragma unroll
    for (int m = 0; m < 4; ++m)
        af[m] = *(const short8_t*)(As + (wv * 64 + m * 16 + (lane & 15)) * 40 + (lane >> 4) * 8);
    #pragma unroll
    for (int nt = 0; nt < 4; ++nt)
        bfr[nt] = *(const short8_t*)(Ws + (nt * 16 + (lane & 15)) * 40 + (lane >> 4) * 8);
    #pragma unroll
    for (int m = 0; m < 4; ++m)
        #pragma unroll
        for (int nt = 0; nt < 4; ++nt)
            acc[m][nt] = __builtin_amdgcn_mfma_f32_16x16x32_bf16(af[m], bfr[nt], acc[m][nt], 0, 0, 0);

    #pragma unroll
    for (int m = 0; m < 4; ++m)
        #pragma unroll
        for (int nt = 0; nt < 4; ++nt)
            #pragma unroll
            for (int j = 0; j < 4; ++j) {
                int row = wv * 64 + m * 16 + (lane >> 4) * 4 + j;
                int nl = row >> 5, bb = row & 31, col = nt * 16 + (lane & 15);
                identt[(size_t)(nbase + nl) * 2048 + bb * 64 + col] = f2bf(acc[m][nt][j]);
            }
}

// ---- per-channel sum / sumsq over a [NOUT][2048] bf16 buffer (channel = idx&63) ----
__global__ __launch_bounds__(256) void reduce_stats_kernel(
    const ushort* __restrict__ src, float* __restrict__ st)
{
    __shared__ float Ls[64], Lq[64];
    const int tid = threadIdx.x;
    if (tid < 64) { Ls[tid] = 0.f; Lq[tid] = 0.f; }
    __syncthreads();
    float s[8], q[8];
    #pragma unroll
    for (int e = 0; e < 8; ++e) { s[e] = 0.f; q[e] = 0.f; }
    size_t base = (size_t)(blockIdx.x * 256 + tid) * 8;
    const size_t stride = (size_t)512 * 256 * 8;
    for (int it = 0; it < 16; ++it, base += stride) {
        int4 v = *(const int4*)(src + base);
        const ushort* pv = (const ushort*)&v;
        #pragma unroll
        for (int e = 0; e < 8; ++e) { float f = bf2f(pv[e]); s[e] += f; q[e] += f * f; }
    }
    const int o0 = (tid * 8) & 63;
    #pragma unroll
    for (int e = 0; e < 8; ++e) { atomicAdd(&Ls[o0 + e], s[e]); atomicAdd(&Lq[o0 + e], q[e]); }
    __syncthreads();
    if (tid < 64) { atomicAdd(&st[tid], Ls[tid]); atomicAdd(&st[64 + tid], Lq[tid]); }
}

// ---- finalize BN affine: a = g*rsqrt(var+eps), c = beta - a*mean ----
__global__ void finalize_kernel(const float* __restrict__ st, const float* __restrict__ g,
                                const float* __restrict__ bet, float* __restrict__ ac)
{
    int o = threadIdx.x;
    if (o >= 64) return;
    float mean = st[o] * (1.0f / MTOT);
    float var  = st[64 + o] * (1.0f / MTOT) - mean * mean;
    float a = g[o] * rsqrtf(var + 1e-5f);
    ac[o] = a;
    ac[64 + o] = bet[o] - a * mean;
}

// ---- in-place bn+relu on out1 ----
__global__ __launch_bounds__(256) void bn_relu_ip_kernel(
    ushort* __restrict__ buf, const float* __restrict__ ac)
{
    const int tid = threadIdx.x;
    const int o0 = (tid * 8) & 63;
    float a[8], c[8];
    #pragma unroll
    for (int e = 0; e < 8; ++e) { a[e] = ac[o0 + e]; c[e] = ac[64 + o0 + e]; }
    size_t base = (size_t)(blockIdx.x * 256 + tid) * 8;
    const size_t stride = (size_t)1024 * 256 * 8;
    for (int it = 0; it < 8; ++it, base += stride) {
        int4 v = *(int4*)(buf + base);
        ushort* pv = (ushort*)&v;
        #pragma unroll
        for (int e = 0; e < 8; ++e) {
            float f = a[e] * bf2f(pv[e]) + c[e];
            pv[e] = f2bf(fmaxf(f, 0.f));
        }
        *(int4*)(buf + base) = v;
    }
}

// ---- final: d_out[bo][n] = relu(a2*out2 + c2 + a3*identt + c3), with transpose ----
__global__ __launch_bounds__(256) void final_combine_kernel(
    const ushort* __restrict__ out2, const ushort* __restrict__ idt,
    const float* __restrict__ ac2, const float* __restrict__ ac3,
    float* __restrict__ dout)
{
    __shared__ float tile[64][65];
    const int tid = threadIdx.x;
    const int n0 = blockIdx.x * 64, bo0 = blockIdx.y * 64;
    const int lane64 = tid & 63, rb = (tid >> 6) * 16;
    const int o = lane64;  // bo0 is a multiple of 64
    const float a2 = ac2[o], c2 = ac2[64 + o], a3 = ac3[o], c3 = ac3[64 + o];
    #pragma unroll
    for (int r = 0; r < 16; ++r) {
        int n_l = rb + r;
        size_t p = (size_t)(n0 + n_l) * 2048 + bo0 + lane64;
        float v = a2 * bf2f(out2[p]) + c2 + a3 * bf2f(idt[p]) + c3;
        tile[n_l][lane64] = fmaxf(v, 0.f);
    }
    __syncthreads();
    #pragma unroll
    for (int r = 0; r < 16; ++r) {
        int bo_l = rb + r;
        dout[(size_t)(bo0 + bo_l) * NOUT + n0 + lane64] = tile[lane64][bo_l];
    }
}

extern "C" void kernel_launch(void* const* d_in, const int* in_sizes, int n_in,
                              void* d_out, int out_size, void* d_ws, size_t ws_size,
                              hipStream_t stream)
{
    const float* x     = (const float*)d_in[0];
    const float* W1    = (const float*)d_in[1];
    const float* W2    = (const float*)d_in[3];
    const float* We    = (const float*)d_in[5];
    const float* g1    = (const float*)d_in[7];
    const float* beta1 = (const float*)d_in[8];
    const float* g2    = (const float*)d_in[9];
    const float* beta2 = (const float*)d_in[10];
    const float* g3    = (const float*)d_in[11];
    const float* beta3 = (const float*)d_in[12];
    const int* idx1    = (const int*)d_in[13];
    const int* idx2    = (const int*)d_in[14];
    const int* pool_idx= (const int*)d_in[15];
    float* dout = (float*)d_out;

    char* ws = (char*)d_ws;
    const size_t off_xt   = 0;                    // 67108864 B
    const size_t off_out1 = 67108864;             // 33554432 B
    const size_t off_out2 = 100663296;            // 33554432 B
    const size_t off_id   = 134217728;            // 33554432 B
    const size_t off_w1p  = 167772160;            // 36864 B
    const size_t off_w2p  = 167809024;            // 73728 B
    const size_t off_wep  = 167882752;            // 4096 B
    const size_t off_st   = 167886848;            // 3*512 B
    const size_t off_ac   = 167888384;            // 3*512 B
    const size_t need     = 167889920;
    if (ws_size < need) return;  // insufficient workspace — fail visibly

    ushort* xt   = (ushort*)(ws + off_xt);
    ushort* out1 = (ushort*)(ws + off_out1);
    ushort* out2 = (ushort*)(ws + off_out2);
    ushort* idt  = (ushort*)(ws + off_id);
    ushort* w1p  = (ushort*)(ws + off_w1p);
    ushort* w2p  = (ushort*)(ws + off_w2p);
    ushort* wep  = (ushort*)(ws + off_wep);
    float*  st1  = (float*)(ws + off_st);
    float*  st2  = st1 + 128;
    float*  st3  = st1 + 256;
    float*  ac1  = (float*)(ws + off_ac);
    float*  ac2  = ac1 + 128;
    float*  ac3  = ac1 + 256;

    hipMemsetAsync(ws + off_st, 0, 3 * 512, stream);

    prep_w_kernel<<<224, 256, 0, stream>>>(W1, W2, We, w1p, w2p, wep);
    transpose_x_kernel<<<dim3(512, 16), 256, 0, stream>>>(x, xt);
    conv1_kernel<<<1024, 256, 0, stream>>>(xt, idx1, w1p, out1);
    reduce_stats_kernel<<<512, 256, 0, stream>>>(out1, st1);
    finalize_kernel<<<1, 64, 0, stream>>>(st1, g1, beta1, ac1);
    bn_relu_ip_kernel<<<1024, 256, 0, stream>>>(out1, ac1);
    conv2_kernel<<<1024, 256, 0, stream>>>(out1, idx2, w2p, out2);
    ident_kernel<<<1024, 256, 0, stream>>>(xt, pool_idx, wep, idt);
    reduce_stats_kernel<<<512, 256, 0, stream>>>(out2, st2);
    reduce_stats_kernel<<<512, 256, 0, stream>>>(idt, st3);
    finalize_kernel<<<1, 64, 0, stream>>>(st2, g2, beta2, ac2);
    finalize_kernel<<<1, 64, 0, stream>>>(st3, g3, beta3, ac3);
    final_combine_kernel<<<dim3(128, 32), 256, 0, stream>>>(out2, idt, ac2, ac3, dout);
}

// Round 2
// 192.243 us; speedup vs baseline: 1.4898x; 1.4898x over previous
//
#include <hip/hip_runtime.h>

typedef __attribute__((ext_vector_type(8))) short short8_t;
typedef __attribute__((ext_vector_type(4))) float f32x4_t;

#define NOUT 8192
#define NIN 32768
#define MTOT 262144.0f   // B * NOUT
#define ST_STRIPES 64

static __device__ __forceinline__ float bf2f(ushort u) {
    union { float f; unsigned int i; } x; x.i = ((unsigned int)u) << 16; return x.f;
}
static __device__ __forceinline__ ushort f2bf(float f) {
    union { float f; unsigned int i; } x; x.f = f;
    unsigned int r = x.i + 0x7fffu + ((x.i >> 16) & 1u);
    return (ushort)(r >> 16);
}

// ---- x [32][32][32768] f32  ->  xt [32768][1024] bf16 (row = b*32+i) ----
__global__ __launch_bounds__(256) void transpose_x_kernel(
    const float* __restrict__ x, ushort* __restrict__ xt)
{
    __shared__ ushort T[64][66];
    const int tid = threadIdx.x;
    const int n0 = blockIdx.x * 64, c0 = blockIdx.y * 64;
    const int lane64 = tid & 63, rb = (tid >> 6) * 16;
    #pragma unroll
    for (int r = 0; r < 16; ++r) {
        int c_l = rb + r;
        T[c_l][lane64] = f2bf(x[(size_t)(c0 + c_l) * NIN + n0 + lane64]);
    }
    __syncthreads();
    #pragma unroll
    for (int r = 0; r < 16; ++r) {
        int n_l = rb + r;
        xt[(size_t)(n0 + n_l) * 1024 + c0 + lane64] = T[lane64][n_l];
    }
}

// ---- weight prep: W1->[9][64][32], W2->[9][64][64], We->[64][32], all bf16 ----
__global__ __launch_bounds__(256) void prep_w_kernel(
    const float* __restrict__ W1, const float* __restrict__ W2,
    const float* __restrict__ We,
    ushort* __restrict__ w1p, ushort* __restrict__ w2p, ushort* __restrict__ wep)
{
    int t = blockIdx.x * 256 + threadIdx.x;
    const int N1 = 9 * 64 * 32, N2 = 9 * 64 * 64, N3 = 64 * 32;
    if (t < N1) {
        int k = t >> 11, rem = t & 2047, o = rem >> 5, i = rem & 31;
        w1p[t] = f2bf(W1[o * 288 + i * 9 + k]);
    } else if (t < N1 + N2) {
        int t2 = t - N1;
        int k = t2 >> 12, rem = t2 & 4095, o = rem >> 6, ci = rem & 63;
        w2p[t2] = f2bf(W2[o * 576 + ci * 9 + k]);
    } else if (t < N1 + N2 + N3) {
        int t3 = t - N1 - N2;
        wep[t3] = f2bf(We[t3]);
    }
}

// ---- conv1: BM=128 (4 n x 32 b), K-step 32 x 9, reg-staged prefetch, fused stats ----
__global__ __launch_bounds__(256) void conv1_kernel(
    const ushort* __restrict__ xt, const int* __restrict__ idx1,
    const ushort* __restrict__ w1p, ushort* __restrict__ out1,
    float* __restrict__ st)
{
    __shared__ ushort As[128 * 40];   // pad 40: stride 80B -> 2-way max
    __shared__ ushort Ws[64 * 40];
    __shared__ float Ls[128];
    const int tid = threadIdx.x;
    const int lane = tid & 63, wv = tid >> 6;
    const int nbase = blockIdx.x * 4;
    const int r_st = tid >> 1, h_st = tid & 1;     // staging: row, 16-ch half
    const int nl_st = tid >> 6, b_st = r_st & 31;
    const int o_st = tid >> 2, sg_st = tid & 3;    // weight staging

    f32x4_t acc[2][4];
    #pragma unroll
    for (int m = 0; m < 2; ++m)
        #pragma unroll
        for (int nt = 0; nt < 4; ++nt) acc[m][nt] = (f32x4_t){0.f, 0.f, 0.f, 0.f};

    // prologue: stage k=0
    {
        int rrow = idx1[(nbase + nl_st) * 9];
        const int4* src = (const int4*)(xt + (size_t)rrow * 1024 + b_st * 32 + h_st * 16);
        int4* dst = (int4*)(As + r_st * 40 + h_st * 16);
        dst[0] = src[0]; dst[1] = src[1];
        const int4* wsrc = (const int4*)(w1p + o_st * 32 + sg_st * 8);
        *(int4*)(Ws + o_st * 40 + sg_st * 8) = wsrc[0];
    }
    if (tid < 128) Ls[tid] = 0.f;
    __syncthreads();

    for (int k = 0; k < 9; ++k) {
        int4 pa0, pa1, pw;
        const bool pre = (k + 1 < 9);
        if (pre) {
            int rrow = idx1[(nbase + nl_st) * 9 + k + 1];
            const int4* src = (const int4*)(xt + (size_t)rrow * 1024 + b_st * 32 + h_st * 16);
            pa0 = src[0]; pa1 = src[1];
            pw = *(const int4*)(w1p + (k + 1) * 2048 + o_st * 32 + sg_st * 8);
        }
        short8_t af[2], bfr[4];
        #pragma unroll
        for (int m = 0; m < 2; ++m)
            af[m] = *(const short8_t*)(As + (wv * 32 + m * 16 + (lane & 15)) * 40 + (lane >> 4) * 8);
        #pragma unroll
        for (int nt = 0; nt < 4; ++nt)
            bfr[nt] = *(const short8_t*)(Ws + (nt * 16 + (lane & 15)) * 40 + (lane >> 4) * 8);
        #pragma unroll
        for (int m = 0; m < 2; ++m)
            #pragma unroll
            for (int nt = 0; nt < 4; ++nt)
                acc[m][nt] = __builtin_amdgcn_mfma_f32_16x16x32_bf16(af[m], bfr[nt], acc[m][nt], 0, 0, 0);
        __syncthreads();
        if (pre) {
            int4* dst = (int4*)(As + r_st * 40 + h_st * 16);
            dst[0] = pa0; dst[1] = pa1;
            *(int4*)(Ws + o_st * 40 + sg_st * 8) = pw;
        }
        __syncthreads();
    }

    // epilogue: store + fused stats
    #pragma unroll
    for (int m = 0; m < 2; ++m)
        #pragma unroll
        for (int nt = 0; nt < 4; ++nt)
            #pragma unroll
            for (int j = 0; j < 4; ++j) {
                int row = wv * 32 + m * 16 + (lane >> 4) * 4 + j;
                int nl = row >> 5, bb = row & 31, col = nt * 16 + (lane & 15);
                out1[(size_t)(nbase + nl) * 2048 + bb * 64 + col] = f2bf(acc[m][nt][j]);
            }
    #pragma unroll
    for (int nt = 0; nt < 4; ++nt) {
        float s = 0.f, q = 0.f;
        #pragma unroll
        for (int m = 0; m < 2; ++m)
            #pragma unroll
            for (int j = 0; j < 4; ++j) { float v = acc[m][nt][j]; s += v; q += v * v; }
        s += __shfl_xor(s, 16); s += __shfl_xor(s, 32);
        q += __shfl_xor(q, 16); q += __shfl_xor(q, 32);
        if (lane < 16) {
            atomicAdd(&Ls[nt * 16 + lane], s);
            atomicAdd(&Ls[64 + nt * 16 + lane], q);
        }
    }
    __syncthreads();
    if (tid < 128) atomicAdd(&st[(blockIdx.x & (ST_STRIPES - 1)) * 128 + tid], Ls[tid]);
}

// ---- conv2: BM=128, K-step 64 x 9, reg-staged prefetch, fused stats ----
__global__ __launch_bounds__(256) void conv2_kernel(
    const ushort* __restrict__ out1n, const int* __restrict__ idx2,
    const ushort* __restrict__ w2p, ushort* __restrict__ out2,
    float* __restrict__ st)
{
    __shared__ ushort As[128 * 72];   // pad 72: stride 144B -> 2-way max
    __shared__ ushort Ws[64 * 72];
    __shared__ float Ls[128];
    const int tid = threadIdx.x;
    const int lane = tid & 63, wv = tid >> 6;
    const int nbase = blockIdx.x * 4;
    const int r_st = tid >> 1, h_st = tid & 1;     // staging: row, 32-ch half
    const int nl_st = tid >> 6, b_st = r_st & 31;
    const int o_st = tid >> 2, sg_st = tid & 3;    // weight staging: 32B each

    f32x4_t acc[2][4];
    #pragma unroll
    for (int m = 0; m < 2; ++m)
        #pragma unroll
        for (int nt = 0; nt < 4; ++nt) acc[m][nt] = (f32x4_t){0.f, 0.f, 0.f, 0.f};

    // prologue: stage k=0
    {
        int rrow = idx2[(nbase + nl_st) * 9];
        const int4* src = (const int4*)(out1n + (size_t)rrow * 2048 + b_st * 64 + h_st * 32);
        int4* dst = (int4*)(As + r_st * 72 + h_st * 32);
        dst[0] = src[0]; dst[1] = src[1]; dst[2] = src[2]; dst[3] = src[3];
        const int4* wsrc = (const int4*)(w2p + o_st * 64 + sg_st * 16);
        int4* wdst = (int4*)(Ws + o_st * 72 + sg_st * 16);
        wdst[0] = wsrc[0]; wdst[1] = wsrc[1];
    }
    if (tid < 128) Ls[tid] = 0.f;
    __syncthreads();

    for (int k = 0; k < 9; ++k) {
        int4 pa0, pa1, pa2, pa3, pw0, pw1;
        const bool pre = (k + 1 < 9);
        if (pre) {
            int rrow = idx2[(nbase + nl_st) * 9 + k + 1];
            const int4* src = (const int4*)(out1n + (size_t)rrow * 2048 + b_st * 64 + h_st * 32);
            pa0 = src[0]; pa1 = src[1]; pa2 = src[2]; pa3 = src[3];
            const int4* wsrc = (const int4*)(w2p + (k + 1) * 4096 + o_st * 64 + sg_st * 16);
            pw0 = wsrc[0]; pw1 = wsrc[1];
        }
        #pragma unroll
        for (int kk = 0; kk < 2; ++kk) {
            short8_t af[2], bfr[4];
            #pragma unroll
            for (int m = 0; m < 2; ++m)
                af[m] = *(const short8_t*)(As + (wv * 32 + m * 16 + (lane & 15)) * 72 + kk * 32 + (lane >> 4) * 8);
            #pragma unroll
            for (int nt = 0; nt < 4; ++nt)
                bfr[nt] = *(const short8_t*)(Ws + (nt * 16 + (lane & 15)) * 72 + kk * 32 + (lane >> 4) * 8);
            #pragma unroll
            for (int m = 0; m < 2; ++m)
                #pragma unroll
                for (int nt = 0; nt < 4; ++nt)
                    acc[m][nt] = __builtin_amdgcn_mfma_f32_16x16x32_bf16(af[m], bfr[nt], acc[m][nt], 0, 0, 0);
        }
        __syncthreads();
        if (pre) {
            int4* dst = (int4*)(As + r_st * 72 + h_st * 32);
            dst[0] = pa0; dst[1] = pa1; dst[2] = pa2; dst[3] = pa3;
            int4* wdst = (int4*)(Ws + o_st * 72 + sg_st * 16);
            wdst[0] = pw0; wdst[1] = pw1;
        }
        __syncthreads();
    }

    // epilogue: store + fused stats
    #pragma unroll
    for (int m = 0; m < 2; ++m)
        #pragma unroll
        for (int nt = 0; nt < 4; ++nt)
            #pragma unroll
            for (int j = 0; j < 4; ++j) {
                int row = wv * 32 + m * 16 + (lane >> 4) * 4 + j;
                int nl = row >> 5, bb = row & 31, col = nt * 16 + (lane & 15);
                out2[(size_t)(nbase + nl) * 2048 + bb * 64 + col] = f2bf(acc[m][nt][j]);
            }
    #pragma unroll
    for (int nt = 0; nt < 4; ++nt) {
        float s = 0.f, q = 0.f;
        #pragma unroll
        for (int m = 0; m < 2; ++m)
            #pragma unroll
            for (int j = 0; j < 4; ++j) { float v = acc[m][nt][j]; s += v; q += v * v; }
        s += __shfl_xor(s, 16); s += __shfl_xor(s, 32);
        q += __shfl_xor(q, 16); q += __shfl_xor(q, 32);
        if (lane < 16) {
            atomicAdd(&Ls[nt * 16 + lane], s);
            atomicAdd(&Ls[64 + nt * 16 + lane], q);
        }
    }
    __syncthreads();
    if (tid < 128) atomicAdd(&st[(blockIdx.x & (ST_STRIPES - 1)) * 128 + tid], Ls[tid]);
}

// ---- identity: pooled-gather x We, fused stats ----
__global__ __launch_bounds__(256) void ident_kernel(
    const ushort* __restrict__ xt, const int* __restrict__ pool_idx,
    const ushort* __restrict__ wep, ushort* __restrict__ identt,
    float* __restrict__ st)
{
    __shared__ ushort As[256 * 40];
    __shared__ ushort Ws[64 * 40];
    __shared__ float Ls[128];
    const int tid = threadIdx.x;
    const int lane = tid & 63, wv = tid >> 6;
    const int nbase = blockIdx.x * 8;
    const int n_l = tid >> 5, b = tid & 31;

    float pa[32];
    #pragma unroll
    for (int i = 0; i < 32; ++i) pa[i] = 0.f;
    for (int kp = 0; kp < 4; ++kp) {
        int rrow = pool_idx[(nbase + n_l) * 4 + kp];
        const int4* src = (const int4*)(xt + (size_t)rrow * 1024 + b * 32);
        #pragma unroll
        for (int j = 0; j < 4; ++j) {
            int4 v = src[j];
            const ushort* pv = (const ushort*)&v;
            #pragma unroll
            for (int e = 0; e < 8; ++e) pa[j * 8 + e] += bf2f(pv[e]);
        }
    }
    {
        int4* dst = (int4*)(As + (n_l * 32 + b) * 40);
        #pragma unroll
        for (int j = 0; j < 4; ++j) {
            int4 v; ushort* pv = (ushort*)&v;
            #pragma unroll
            for (int e = 0; e < 8; ++e) pv[e] = f2bf(pa[j * 8 + e] * 0.25f);
            dst[j] = v;
        }
    }
    {
        int o = tid >> 2, seg = tid & 3;
        *(int4*)(Ws + o * 40 + seg * 8) = *(const int4*)(wep + o * 32 + seg * 8);
    }
    if (tid < 128) Ls[tid] = 0.f;
    __syncthreads();

    f32x4_t acc[4][4];
    #pragma unroll
    for (int m = 0; m < 4; ++m)
        #pragma unroll
        for (int nt = 0; nt < 4; ++nt) acc[m][nt] = (f32x4_t){0.f, 0.f, 0.f, 0.f};
    short8_t af[4], bfr[4];
    #pragma unroll
    for (int m = 0; m < 4; ++m)
        af[m] = *(const short8_t*)(As + (wv * 64 + m * 16 + (lane & 15)) * 40 + (lane >> 4) * 8);
    #pragma unroll
    for (int nt = 0; nt < 4; ++nt)
        bfr[nt] = *(const short8_t*)(Ws + (nt * 16 + (lane & 15)) * 40 + (lane >> 4) * 8);
    #pragma unroll
    for (int m = 0; m < 4; ++m)
        #pragma unroll
        for (int nt = 0; nt < 4; ++nt)
            acc[m][nt] = __builtin_amdgcn_mfma_f32_16x16x32_bf16(af[m], bfr[nt], acc[m][nt], 0, 0, 0);

    #pragma unroll
    for (int m = 0; m < 4; ++m)
        #pragma unroll
        for (int nt = 0; nt < 4; ++nt)
            #pragma unroll
            for (int j = 0; j < 4; ++j) {
                int row = wv * 64 + m * 16 + (lane >> 4) * 4 + j;
                int nl = row >> 5, bb = row & 31, col = nt * 16 + (lane & 15);
                identt[(size_t)(nbase + nl) * 2048 + bb * 64 + col] = f2bf(acc[m][nt][j]);
            }
    #pragma unroll
    for (int nt = 0; nt < 4; ++nt) {
        float s = 0.f, q = 0.f;
        #pragma unroll
        for (int m = 0; m < 4; ++m)
            #pragma unroll
            for (int j = 0; j < 4; ++j) { float v = acc[m][nt][j]; s += v; q += v * v; }
        s += __shfl_xor(s, 16); s += __shfl_xor(s, 32);
        q += __shfl_xor(q, 16); q += __shfl_xor(q, 32);
        if (lane < 16) {
            atomicAdd(&Ls[nt * 16 + lane], s);
            atomicAdd(&Ls[64 + nt * 16 + lane], q);
        }
    }
    __syncthreads();
    if (tid < 128) atomicAdd(&st[(blockIdx.x & (ST_STRIPES - 1)) * 128 + tid], Ls[tid]);
}

// ---- finalize BN affine from striped partials: a = g*rsqrt(var+eps), c = beta - a*mean ----
__global__ void finalize_kernel(const float* __restrict__ st, const float* __restrict__ g,
                                const float* __restrict__ bet, float* __restrict__ ac)
{
    int o = threadIdx.x;
    if (o >= 64) return;
    float s = 0.f, q = 0.f;
    for (int i = 0; i < ST_STRIPES; ++i) { s += st[i * 128 + o]; q += st[i * 128 + 64 + o]; }
    float mean = s * (1.0f / MTOT);
    float var  = q * (1.0f / MTOT) - mean * mean;
    float a = g[o] * rsqrtf(var + 1e-5f);
    ac[o] = a;
    ac[64 + o] = bet[o] - a * mean;
}

// ---- in-place bn+relu on out1 ----
__global__ __launch_bounds__(256) void bn_relu_ip_kernel(
    ushort* __restrict__ buf, const float* __restrict__ ac)
{
    const int tid = threadIdx.x;
    const int o0 = (tid * 8) & 63;
    float a[8], c[8];
    #pragma unroll
    for (int e = 0; e < 8; ++e) { a[e] = ac[o0 + e]; c[e] = ac[64 + o0 + e]; }
    size_t base = (size_t)(blockIdx.x * 256 + tid) * 8;
    const size_t stride = (size_t)1024 * 256 * 8;
    for (int it = 0; it < 8; ++it, base += stride) {
        int4 v = *(int4*)(buf + base);
        ushort* pv = (ushort*)&v;
        #pragma unroll
        for (int e = 0; e < 8; ++e) {
            float f = a[e] * bf2f(pv[e]) + c[e];
            pv[e] = f2bf(fmaxf(f, 0.f));
        }
        *(int4*)(buf + base) = v;
    }
}

// ---- final: d_out[bo][n] = relu(a2*out2 + c2 + a3*identt + c3), with transpose ----
__global__ __launch_bounds__(256) void final_combine_kernel(
    const ushort* __restrict__ out2, const ushort* __restrict__ idt,
    const float* __restrict__ ac2, const float* __restrict__ ac3,
    float* __restrict__ dout)
{
    __shared__ float tile[64][65];
    const int tid = threadIdx.x;
    const int n0 = blockIdx.x * 64, bo0 = blockIdx.y * 64;
    const int lane64 = tid & 63, rb = (tid >> 6) * 16;
    const int o = lane64;  // bo0 is a multiple of 64
    const float a2 = ac2[o], c2 = ac2[64 + o], a3 = ac3[o], c3 = ac3[64 + o];
    #pragma unroll
    for (int r = 0; r < 16; ++r) {
        int n_l = rb + r;
        size_t p = (size_t)(n0 + n_l) * 2048 + bo0 + lane64;
        float v = a2 * bf2f(out2[p]) + c2 + a3 * bf2f(idt[p]) + c3;
        tile[n_l][lane64] = fmaxf(v, 0.f);
    }
    __syncthreads();
    #pragma unroll
    for (int r = 0; r < 16; ++r) {
        int bo_l = rb + r;
        dout[(size_t)(bo0 + bo_l) * NOUT + n0 + lane64] = tile[lane64][bo_l];
    }
}

extern "C" void kernel_launch(void* const* d_in, const int* in_sizes, int n_in,
                              void* d_out, int out_size, void* d_ws, size_t ws_size,
                              hipStream_t stream)
{
    const float* x     = (const float*)d_in[0];
    const float* W1    = (const float*)d_in[1];
    const float* W2    = (const float*)d_in[3];
    const float* We    = (const float*)d_in[5];
    const float* g1    = (const float*)d_in[7];
    const float* beta1 = (const float*)d_in[8];
    const float* g2    = (const float*)d_in[9];
    const float* beta2 = (const float*)d_in[10];
    const float* g3    = (const float*)d_in[11];
    const float* beta3 = (const float*)d_in[12];
    const int* idx1    = (const int*)d_in[13];
    const int* idx2    = (const int*)d_in[14];
    const int* pool_idx= (const int*)d_in[15];
    float* dout = (float*)d_out;

    char* ws = (char*)d_ws;
    const size_t off_xt   = 0;                    // 67108864
    const size_t off_out1 = 67108864;             // 33554432
    const size_t off_out2 = 100663296;            // 33554432
    const size_t off_id   = 134217728;            // 33554432
    const size_t off_w1p  = 167772160;             // 36864
    const size_t off_w2p  = 167809024;             // 73728
    const size_t off_wep  = 167882752;             // 4096
    const size_t off_st   = 167886848;             // 3 * 64*128*4 = 98304
    const size_t off_ac   = 167985152;             // 1536
    const size_t need     = 167986688;
    if (ws_size < need) return;  // insufficient workspace — fail visibly

    ushort* xt   = (ushort*)(ws + off_xt);
    ushort* out1 = (ushort*)(ws + off_out1);
    ushort* out2 = (ushort*)(ws + off_out2);
    ushort* idt  = (ushort*)(ws + off_id);
    ushort* w1p  = (ushort*)(ws + off_w1p);
    ushort* w2p  = (ushort*)(ws + off_w2p);
    ushort* wep  = (ushort*)(ws + off_wep);
    float*  st1  = (float*)(ws + off_st);
    float*  st2  = st1 + 64 * 128;
    float*  st3  = st1 + 2 * 64 * 128;
    float*  ac1  = (float*)(ws + off_ac);
    float*  ac2  = ac1 + 128;
    float*  ac3  = ac1 + 256;

    hipMemsetAsync(ws + off_st, 0, 3 * 64 * 128 * 4, stream);

    prep_w_kernel<<<224, 256, 0, stream>>>(W1, W2, We, w1p, w2p, wep);
    transpose_x_kernel<<<dim3(512, 16), 256, 0, stream>>>(x, xt);
    conv1_kernel<<<2048, 256, 0, stream>>>(xt, idx1, w1p, out1, st1);
    finalize_kernel<<<1, 64, 0, stream>>>(st1, g1, beta1, ac1);
    bn_relu_ip_kernel<<<1024, 256, 0, stream>>>(out1, ac1);
    conv2_kernel<<<2048, 256, 0, stream>>>(out1, idx2, w2p, out2, st2);
    ident_kernel<<<1024, 256, 0, stream>>>(xt, pool_idx, wep, idt, st3);
    finalize_kernel<<<1, 64, 0, stream>>>(st2, g2, beta2, ac2);
    finalize_kernel<<<1, 64, 0, stream>>>(st3, g3, beta3, ac3);
    final_combine_kernel<<<dim3(128, 32), 256, 0, stream>>>(out2, idt, ac2, ac3, dout);
}

// Round 3
// 190.958 us; speedup vs baseline: 1.4998x; 1.0067x over previous
//
#include <hip/hip_runtime.h>

typedef __attribute__((ext_vector_type(8))) short short8_t;
typedef __attribute__((ext_vector_type(4))) float f32x4_t;

#define NOUT 8192
#define NIN 32768
#define MTOT 262144.0f   // B * NOUT
#define ST_STRIPES 64

static __device__ __forceinline__ float bf2f(ushort u) {
    union { float f; unsigned int i; } x; x.i = ((unsigned int)u) << 16; return x.f;
}
static __device__ __forceinline__ ushort f2bf(float f) {
    union { float f; unsigned int i; } x; x.f = f;
    unsigned int r = x.i + 0x7fffu + ((x.i >> 16) & 1u);
    return (ushort)(r >> 16);
}

// apply BN1+ReLU to 8 packed bf16 (channels ch0..ch0+7), acs = [a[64], c[64]] in LDS
static __device__ __forceinline__ int4 bnx(int4 v, const float* __restrict__ acs, int ch0) {
    ushort* pv = (ushort*)&v;
    #pragma unroll
    for (int e = 0; e < 8; ++e) {
        float f = acs[ch0 + e] * bf2f(pv[e]) + acs[64 + ch0 + e];
        pv[e] = f2bf(fmaxf(f, 0.f));
    }
    return v;
}

// ---- x [32][32][32768] f32  ->  xt [32768][1024] bf16 (row = b*32+i) ----
__global__ __launch_bounds__(256) void transpose_x_kernel(
    const float* __restrict__ x, ushort* __restrict__ xt)
{
    __shared__ ushort T[64][66];
    const int tid = threadIdx.x;
    const int n0 = blockIdx.x * 64, c0 = blockIdx.y * 64;
    const int lane64 = tid & 63, rb = (tid >> 6) * 16;
    #pragma unroll
    for (int r = 0; r < 16; ++r) {
        int c_l = rb + r;
        T[c_l][lane64] = f2bf(x[(size_t)(c0 + c_l) * NIN + n0 + lane64]);
    }
    __syncthreads();
    #pragma unroll
    for (int r = 0; r < 16; ++r) {
        int n_l = rb + r;
        xt[(size_t)(n0 + n_l) * 1024 + c0 + lane64] = T[lane64][n_l];
    }
}

// ---- weight prep (+ zero the stats stripes; replaces in-graph hipMemsetAsync) ----
__global__ __launch_bounds__(256) void prep_w_kernel(
    const float* __restrict__ W1, const float* __restrict__ W2,
    const float* __restrict__ We,
    ushort* __restrict__ w1p, ushort* __restrict__ w2p, ushort* __restrict__ wep,
    float* __restrict__ stz)
{
    int t = blockIdx.x * 256 + threadIdx.x;
    const int N1 = 9 * 64 * 32, N2 = 9 * 64 * 64, N3 = 64 * 32;
    if (t < 3 * ST_STRIPES * 128) stz[t] = 0.f;
    if (t < N1) {
        int k = t >> 11, rem = t & 2047, o = rem >> 5, i = rem & 31;
        w1p[t] = f2bf(W1[o * 288 + i * 9 + k]);
    } else if (t < N1 + N2) {
        int t2 = t - N1;
        int k = t2 >> 12, rem = t2 & 4095, o = rem >> 6, ci = rem & 63;
        w2p[t2] = f2bf(W2[o * 576 + ci * 9 + k]);
    } else if (t < N1 + N2 + N3) {
        int t3 = t - N1 - N2;
        wep[t3] = f2bf(We[t3]);
    }
}

// ---- conv1: BM=128 (4 n x 32 b), K-step 32 x 9, reg-staged prefetch, fused stats ----
__global__ __launch_bounds__(256) void conv1_kernel(
    const ushort* __restrict__ xt, const int* __restrict__ idx1,
    const ushort* __restrict__ w1p, ushort* __restrict__ out1,
    float* __restrict__ st)
{
    __shared__ ushort As[128 * 40];   // pad 40: stride 80B -> 2-way max
    __shared__ ushort Ws[64 * 40];
    __shared__ float Ls[128];
    const int tid = threadIdx.x;
    const int lane = tid & 63, wv = tid >> 6;
    const int nbase = blockIdx.x * 4;
    const int r_st = tid >> 1, h_st = tid & 1;     // staging: row, 16-ch half
    const int nl_st = tid >> 6, b_st = r_st & 31;
    const int o_st = tid >> 2, sg_st = tid & 3;    // weight staging

    f32x4_t acc[2][4];
    #pragma unroll
    for (int m = 0; m < 2; ++m)
        #pragma unroll
        for (int nt = 0; nt < 4; ++nt) acc[m][nt] = (f32x4_t){0.f, 0.f, 0.f, 0.f};

    // prologue: stage k=0
    {
        int rrow = idx1[(nbase + nl_st) * 9];
        const int4* src = (const int4*)(xt + (size_t)rrow * 1024 + b_st * 32 + h_st * 16);
        int4* dst = (int4*)(As + r_st * 40 + h_st * 16);
        dst[0] = src[0]; dst[1] = src[1];
        const int4* wsrc = (const int4*)(w1p + o_st * 32 + sg_st * 8);
        *(int4*)(Ws + o_st * 40 + sg_st * 8) = wsrc[0];
    }
    if (tid < 128) Ls[tid] = 0.f;
    __syncthreads();

    for (int k = 0; k < 9; ++k) {
        int4 pa0, pa1, pw;
        const bool pre = (k + 1 < 9);
        if (pre) {
            int rrow = idx1[(nbase + nl_st) * 9 + k + 1];
            const int4* src = (const int4*)(xt + (size_t)rrow * 1024 + b_st * 32 + h_st * 16);
            pa0 = src[0]; pa1 = src[1];
            pw = *(const int4*)(w1p + (k + 1) * 2048 + o_st * 32 + sg_st * 8);
        }
        short8_t af[2], bfr[4];
        #pragma unroll
        for (int m = 0; m < 2; ++m)
            af[m] = *(const short8_t*)(As + (wv * 32 + m * 16 + (lane & 15)) * 40 + (lane >> 4) * 8);
        #pragma unroll
        for (int nt = 0; nt < 4; ++nt)
            bfr[nt] = *(const short8_t*)(Ws + (nt * 16 + (lane & 15)) * 40 + (lane >> 4) * 8);
        #pragma unroll
        for (int m = 0; m < 2; ++m)
            #pragma unroll
            for (int nt = 0; nt < 4; ++nt)
                acc[m][nt] = __builtin_amdgcn_mfma_f32_16x16x32_bf16(af[m], bfr[nt], acc[m][nt], 0, 0, 0);
        __syncthreads();
        if (pre) {
            int4* dst = (int4*)(As + r_st * 40 + h_st * 16);
            dst[0] = pa0; dst[1] = pa1;
            *(int4*)(Ws + o_st * 40 + sg_st * 8) = pw;
        }
        __syncthreads();
    }

    // epilogue: store + fused stats
    #pragma unroll
    for (int m = 0; m < 2; ++m)
        #pragma unroll
        for (int nt = 0; nt < 4; ++nt)
            #pragma unroll
            for (int j = 0; j < 4; ++j) {
                int row = wv * 32 + m * 16 + (lane >> 4) * 4 + j;
                int nl = row >> 5, bb = row & 31, col = nt * 16 + (lane & 15);
                out1[(size_t)(nbase + nl) * 2048 + bb * 64 + col] = f2bf(acc[m][nt][j]);
            }
    #pragma unroll
    for (int nt = 0; nt < 4; ++nt) {
        float s = 0.f, q = 0.f;
        #pragma unroll
        for (int m = 0; m < 2; ++m)
            #pragma unroll
            for (int j = 0; j < 4; ++j) { float v = acc[m][nt][j]; s += v; q += v * v; }
        s += __shfl_xor(s, 16); s += __shfl_xor(s, 32);
        q += __shfl_xor(q, 16); q += __shfl_xor(q, 32);
        if (lane < 16) {
            atomicAdd(&Ls[nt * 16 + lane], s);
            atomicAdd(&Ls[64 + nt * 16 + lane], q);
        }
    }
    __syncthreads();
    if (tid < 128) atomicAdd(&st[(blockIdx.x & (ST_STRIPES - 1)) * 128 + tid], Ls[tid]);
}

// ---- conv2: BM=128, K-step 64 x 9, reg-staged prefetch, fused BN1+ReLU on load, fused stats ----
__global__ __launch_bounds__(256) void conv2_kernel(
    const ushort* __restrict__ out1raw, const int* __restrict__ idx2,
    const ushort* __restrict__ w2p, const float* __restrict__ ac1,
    ushort* __restrict__ out2, float* __restrict__ st)
{
    __shared__ ushort As[128 * 72];   // pad 72: stride 144B -> 2-way max
    __shared__ ushort Ws[64 * 72];
    __shared__ float Ls[128];
    __shared__ float ACs[128];
    const int tid = threadIdx.x;
    const int lane = tid & 63, wv = tid >> 6;
    const int nbase = blockIdx.x * 4;
    const int r_st = tid >> 1, h_st = tid & 1;     // staging: row, 32-ch half
    const int nl_st = tid >> 6, b_st = r_st & 31;
    const int o_st = tid >> 2, sg_st = tid & 3;    // weight staging: 32B each
    const int ch0 = h_st * 32;

    f32x4_t acc[2][4];
    #pragma unroll
    for (int m = 0; m < 2; ++m)
        #pragma unroll
        for (int nt = 0; nt < 4; ++nt) acc[m][nt] = (f32x4_t){0.f, 0.f, 0.f, 0.f};

    if (tid < 128) { ACs[tid] = ac1[tid]; Ls[tid] = 0.f; }

    // prologue: gather k=0 raw into regs, weights into LDS
    int4 q0, q1, q2, q3;
    {
        int rrow = idx2[(nbase + nl_st) * 9];
        const int4* src = (const int4*)(out1raw + (size_t)rrow * 2048 + b_st * 64 + h_st * 32);
        q0 = src[0]; q1 = src[1]; q2 = src[2]; q3 = src[3];
        const int4* wsrc = (const int4*)(w2p + o_st * 64 + sg_st * 16);
        int4* wdst = (int4*)(Ws + o_st * 72 + sg_st * 16);
        wdst[0] = wsrc[0]; wdst[1] = wsrc[1];
    }
    __syncthreads();   // ACs visible
    {
        int4* dst = (int4*)(As + r_st * 72 + h_st * 32);
        dst[0] = bnx(q0, ACs, ch0);
        dst[1] = bnx(q1, ACs, ch0 + 8);
        dst[2] = bnx(q2, ACs, ch0 + 16);
        dst[3] = bnx(q3, ACs, ch0 + 24);
    }
    __syncthreads();

    for (int k = 0; k < 9; ++k) {
        int4 pa0, pa1, pa2, pa3, pw0, pw1;
        const bool pre = (k + 1 < 9);
        if (pre) {
            int rrow = idx2[(nbase + nl_st) * 9 + k + 1];
            const int4* src = (const int4*)(out1raw + (size_t)rrow * 2048 + b_st * 64 + h_st * 32);
            pa0 = src[0]; pa1 = src[1]; pa2 = src[2]; pa3 = src[3];
            const int4* wsrc = (const int4*)(w2p + (k + 1) * 4096 + o_st * 64 + sg_st * 16);
            pw0 = wsrc[0]; pw1 = wsrc[1];
        }
        #pragma unroll
        for (int kk = 0; kk < 2; ++kk) {
            short8_t af[2], bfr[4];
            #pragma unroll
            for (int m = 0; m < 2; ++m)
                af[m] = *(const short8_t*)(As + (wv * 32 + m * 16 + (lane & 15)) * 72 + kk * 32 + (lane >> 4) * 8);
            #pragma unroll
            for (int nt = 0; nt < 4; ++nt)
                bfr[nt] = *(const short8_t*)(Ws + (nt * 16 + (lane & 15)) * 72 + kk * 32 + (lane >> 4) * 8);
            #pragma unroll
            for (int m = 0; m < 2; ++m)
                #pragma unroll
                for (int nt = 0; nt < 4; ++nt)
                    acc[m][nt] = __builtin_amdgcn_mfma_f32_16x16x32_bf16(af[m], bfr[nt], acc[m][nt], 0, 0, 0);
        }
        if (pre) {   // transform prefetched data in regs (overlaps MFMA drain)
            pa0 = bnx(pa0, ACs, ch0);
            pa1 = bnx(pa1, ACs, ch0 + 8);
            pa2 = bnx(pa2, ACs, ch0 + 16);
            pa3 = bnx(pa3, ACs, ch0 + 24);
        }
        __syncthreads();
        if (pre) {
            int4* dst = (int4*)(As + r_st * 72 + h_st * 32);
            dst[0] = pa0; dst[1] = pa1; dst[2] = pa2; dst[3] = pa3;
            int4* wdst = (int4*)(Ws + o_st * 72 + sg_st * 16);
            wdst[0] = pw0; wdst[1] = pw1;
        }
        __syncthreads();
    }

    // epilogue: store + fused stats
    #pragma unroll
    for (int m = 0; m < 2; ++m)
        #pragma unroll
        for (int nt = 0; nt < 4; ++nt)
            #pragma unroll
            for (int j = 0; j < 4; ++j) {
                int row = wv * 32 + m * 16 + (lane >> 4) * 4 + j;
                int nl = row >> 5, bb = row & 31, col = nt * 16 + (lane & 15);
                out2[(size_t)(nbase + nl) * 2048 + bb * 64 + col] = f2bf(acc[m][nt][j]);
            }
    #pragma unroll
    for (int nt = 0; nt < 4; ++nt) {
        float s = 0.f, q = 0.f;
        #pragma unroll
        for (int m = 0; m < 2; ++m)
            #pragma unroll
            for (int j = 0; j < 4; ++j) { float v = acc[m][nt][j]; s += v; q += v * v; }
        s += __shfl_xor(s, 16); s += __shfl_xor(s, 32);
        q += __shfl_xor(q, 16); q += __shfl_xor(q, 32);
        if (lane < 16) {
            atomicAdd(&Ls[nt * 16 + lane], s);
            atomicAdd(&Ls[64 + nt * 16 + lane], q);
        }
    }
    __syncthreads();
    if (tid < 128) atomicAdd(&st[(blockIdx.x & (ST_STRIPES - 1)) * 128 + tid], Ls[tid]);
}

// ---- identity: pooled-gather x We, fused stats ----
__global__ __launch_bounds__(256) void ident_kernel(
    const ushort* __restrict__ xt, const int* __restrict__ pool_idx,
    const ushort* __restrict__ wep, ushort* __restrict__ identt,
    float* __restrict__ st)
{
    __shared__ ushort As[256 * 40];
    __shared__ ushort Ws[64 * 40];
    __shared__ float Ls[128];
    const int tid = threadIdx.x;
    const int lane = tid & 63, wv = tid >> 6;
    const int nbase = blockIdx.x * 8;
    const int n_l = tid >> 5, b = tid & 31;

    float pa[32];
    #pragma unroll
    for (int i = 0; i < 32; ++i) pa[i] = 0.f;
    for (int kp = 0; kp < 4; ++kp) {
        int rrow = pool_idx[(nbase + n_l) * 4 + kp];
        const int4* src = (const int4*)(xt + (size_t)rrow * 1024 + b * 32);
        #pragma unroll
        for (int j = 0; j < 4; ++j) {
            int4 v = src[j];
            const ushort* pv = (const ushort*)&v;
            #pragma unroll
            for (int e = 0; e < 8; ++e) pa[j * 8 + e] += bf2f(pv[e]);
        }
    }
    {
        int4* dst = (int4*)(As + (n_l * 32 + b) * 40);
        #pragma unroll
        for (int j = 0; j < 4; ++j) {
            int4 v; ushort* pv = (ushort*)&v;
            #pragma unroll
            for (int e = 0; e < 8; ++e) pv[e] = f2bf(pa[j * 8 + e] * 0.25f);
            dst[j] = v;
        }
    }
    {
        int o = tid >> 2, seg = tid & 3;
        *(int4*)(Ws + o * 40 + seg * 8) = *(const int4*)(wep + o * 32 + seg * 8);
    }
    if (tid < 128) Ls[tid] = 0.f;
    __syncthreads();

    f32x4_t acc[4][4];
    #pragma unroll
    for (int m = 0; m < 4; ++m)
        #pragma unroll
        for (int nt = 0; nt < 4; ++nt) acc[m][nt] = (f32x4_t){0.f, 0.f, 0.f, 0.f};
    short8_t af[4], bfr[4];
    #pragma unroll
    for (int m = 0; m < 4; ++m)
        af[m] = *(const short8_t*)(As + (wv * 64 + m * 16 + (lane & 15)) * 40 + (lane >> 4) * 8);
    #pragma unroll
    for (int nt = 0; nt < 4; ++nt)
        bfr[nt] = *(const short8_t*)(Ws + (nt * 16 + (lane & 15)) * 40 + (lane >> 4) * 8);
    #pragma unroll
    for (int m = 0; m < 4; ++m)
        #pragma unroll
        for (int nt = 0; nt < 4; ++nt)
            acc[m][nt] = __builtin_amdgcn_mfma_f32_16x16x32_bf16(af[m], bfr[nt], acc[m][nt], 0, 0, 0);

    #pragma unroll
    for (int m = 0; m < 4; ++m)
        #pragma unroll
        for (int nt = 0; nt < 4; ++nt)
            #pragma unroll
            for (int j = 0; j < 4; ++j) {
                int row = wv * 64 + m * 16 + (lane >> 4) * 4 + j;
                int nl = row >> 5, bb = row & 31, col = nt * 16 + (lane & 15);
                identt[(size_t)(nbase + nl) * 2048 + bb * 64 + col] = f2bf(acc[m][nt][j]);
            }
    #pragma unroll
    for (int nt = 0; nt < 4; ++nt) {
        float s = 0.f, q = 0.f;
        #pragma unroll
        for (int m = 0; m < 4; ++m)
            #pragma unroll
            for (int j = 0; j < 4; ++j) { float v = acc[m][nt][j]; s += v; q += v * v; }
        s += __shfl_xor(s, 16); s += __shfl_xor(s, 32);
        q += __shfl_xor(q, 16); q += __shfl_xor(q, 32);
        if (lane < 16) {
            atomicAdd(&Ls[nt * 16 + lane], s);
            atomicAdd(&Ls[64 + nt * 16 + lane], q);
        }
    }
    __syncthreads();
    if (tid < 128) atomicAdd(&st[(blockIdx.x & (ST_STRIPES - 1)) * 128 + tid], Ls[tid]);
}

// ---- finalize BN affine from striped partials: a = g*rsqrt(var+eps), c = beta - a*mean ----
__global__ void finalize_kernel(const float* __restrict__ st, const float* __restrict__ g,
                                const float* __restrict__ bet, float* __restrict__ ac)
{
    int o = threadIdx.x;
    if (o >= 64) return;
    float s = 0.f, q = 0.f;
    for (int i = 0; i < ST_STRIPES; ++i) { s += st[i * 128 + o]; q += st[i * 128 + 64 + o]; }
    float mean = s * (1.0f / MTOT);
    float var  = q * (1.0f / MTOT) - mean * mean;
    float a = g[o] * rsqrtf(var + 1e-5f);
    ac[o] = a;
    ac[64 + o] = bet[o] - a * mean;
}

// ---- finalize for layers 2 and 3 in one dispatch (blockIdx 0 -> BN2, 1 -> BN3) ----
__global__ void finalize23_kernel(
    const float* __restrict__ st2, const float* __restrict__ g2, const float* __restrict__ b2,
    const float* __restrict__ st3, const float* __restrict__ g3, const float* __restrict__ b3,
    float* __restrict__ ac2, float* __restrict__ ac3)
{
    int o = threadIdx.x;
    if (o >= 64) return;
    const float* st = blockIdx.x ? st3 : st2;
    const float* g  = blockIdx.x ? g3  : g2;
    const float* bt = blockIdx.x ? b3  : b2;
    float* ac       = blockIdx.x ? ac3 : ac2;
    float s = 0.f, q = 0.f;
    for (int i = 0; i < ST_STRIPES; ++i) { s += st[i * 128 + o]; q += st[i * 128 + 64 + o]; }
    float mean = s * (1.0f / MTOT);
    float var  = q * (1.0f / MTOT) - mean * mean;
    float a = g[o] * rsqrtf(var + 1e-5f);
    ac[o] = a;
    ac[64 + o] = bt[o] - a * mean;
}

// ---- final: d_out[bo][n] = relu(a2*out2 + c2 + a3*identt + c3), with transpose ----
__global__ __launch_bounds__(256) void final_combine_kernel(
    const ushort* __restrict__ out2, const ushort* __restrict__ idt,
    const float* __restrict__ ac2, const float* __restrict__ ac3,
    float* __restrict__ dout)
{
    __shared__ float tile[64][65];
    const int tid = threadIdx.x;
    const int n0 = blockIdx.x * 64, bo0 = blockIdx.y * 64;
    const int lane64 = tid & 63, rb = (tid >> 6) * 16;
    const int o = lane64;  // bo0 is a multiple of 64
    const float a2 = ac2[o], c2 = ac2[64 + o], a3 = ac3[o], c3 = ac3[64 + o];
    #pragma unroll
    for (int r = 0; r < 16; ++r) {
        int n_l = rb + r;
        size_t p = (size_t)(n0 + n_l) * 2048 + bo0 + lane64;
        float v = a2 * bf2f(out2[p]) + c2 + a3 * bf2f(idt[p]) + c3;
        tile[n_l][lane64] = fmaxf(v, 0.f);
    }
    __syncthreads();
    #pragma unroll
    for (int r = 0; r < 16; ++r) {
        int bo_l = rb + r;
        dout[(size_t)(bo0 + bo_l) * NOUT + n0 + lane64] = tile[lane64][bo_l];
    }
}

extern "C" void kernel_launch(void* const* d_in, const int* in_sizes, int n_in,
                              void* d_out, int out_size, void* d_ws, size_t ws_size,
                              hipStream_t stream)
{
    const float* x     = (const float*)d_in[0];
    const float* W1    = (const float*)d_in[1];
    const float* W2    = (const float*)d_in[3];
    const float* We    = (const float*)d_in[5];
    const float* g1    = (const float*)d_in[7];
    const float* beta1 = (const float*)d_in[8];
    const float* g2    = (const float*)d_in[9];
    const float* beta2 = (const float*)d_in[10];
    const float* g3    = (const float*)d_in[11];
    const float* beta3 = (const float*)d_in[12];
    const int* idx1    = (const int*)d_in[13];
    const int* idx2    = (const int*)d_in[14];
    const int* pool_idx= (const int*)d_in[15];
    float* dout = (float*)d_out;

    char* ws = (char*)d_ws;
    const size_t off_xt   = 0;                    // 67108864
    const size_t off_out1 = 67108864;             // 33554432
    const size_t off_out2 = 100663296;            // 33554432
    const size_t off_id   = 134217728;            // 33554432
    const size_t off_w1p  = 167772160;             // 36864
    const size_t off_w2p  = 167809024;             // 73728
    const size_t off_wep  = 167882752;             // 4096
    const size_t off_st   = 167886848;             // 3 * 64*128*4 = 98304
    const size_t off_ac   = 167985152;             // 1536
    const size_t need     = 167986688;
    if (ws_size < need) return;  // insufficient workspace — fail visibly

    ushort* xt   = (ushort*)(ws + off_xt);
    ushort* out1 = (ushort*)(ws + off_out1);
    ushort* out2 = (ushort*)(ws + off_out2);
    ushort* idt  = (ushort*)(ws + off_id);
    ushort* w1p  = (ushort*)(ws + off_w1p);
    ushort* w2p  = (ushort*)(ws + off_w2p);
    ushort* wep  = (ushort*)(ws + off_wep);
    float*  st1  = (float*)(ws + off_st);
    float*  st2  = st1 + 64 * 128;
    float*  st3  = st1 + 2 * 64 * 128;
    float*  ac1  = (float*)(ws + off_ac);
    float*  ac2  = ac1 + 128;
    float*  ac3  = ac1 + 256;

    prep_w_kernel<<<224, 256, 0, stream>>>(W1, W2, We, w1p, w2p, wep, st1);
    transpose_x_kernel<<<dim3(512, 16), 256, 0, stream>>>(x, xt);
    conv1_kernel<<<2048, 256, 0, stream>>>(xt, idx1, w1p, out1, st1);
    ident_kernel<<<1024, 256, 0, stream>>>(xt, pool_idx, wep, idt, st3);
    finalize_kernel<<<1, 64, 0, stream>>>(st1, g1, beta1, ac1);
    conv2_kernel<<<2048, 256, 0, stream>>>(out1, idx2, w2p, ac1, out2, st2);
    finalize23_kernel<<<2, 64, 0, stream>>>(st2, g2, beta2, st3, g3, beta3, ac2, ac3);
    final_combine_kernel<<<dim3(128, 32), 256, 0, stream>>>(out2, idt, ac2, ac3, dout);
}